// Round 1
// baseline (953.268 us; speedup 1.0000x reference)
//
#include <hip/hip_runtime.h>
#include <hip/hip_bf16.h>
#include <stdint.h>

#define B_ 2
#define N_ 2048
#define D_ 1024
#define H_ 16
#define MM 4096
#define NN 1024
#define KK 1024

typedef __bf16 bf16;
typedef __bf16 bf16x8 __attribute__((ext_vector_type(8)));
typedef float f32x4 __attribute__((ext_vector_type(4)));

struct __align__(8) bf4 { bf16 v[4]; };

// LDS row stride: 64 bf16 + 8 pad = 144 bytes (conflict-free frag reads: bank
// base = row*36 mod 32 = 4*row → rows 0..7 hit distinct 4-bank sets, rows 8..15
// alias 2-way which is free)
#define LDS_STRIDE 144

// ---------------------------------------------------------------- conversions
__global__ __launch_bounds__(256) void k_cvt(const float* __restrict__ x,
                                             bf16* __restrict__ y) {
    size_t i = (size_t)blockIdx.x * 256 + threadIdx.x;
    f32x4 f = ((const f32x4*)x)[i];
    bf4 o;
#pragma unroll
    for (int j = 0; j < 4; ++j) o.v[j] = (bf16)f[j];
    ((bf4*)y)[i] = o;
}

// Wt[n][k] = (bf16)W[k][n]  (1024x1024)
__global__ void k_wtt(const float* __restrict__ W, bf16* __restrict__ Wt) {
    __shared__ float t[32][33];
    int bx = blockIdx.x * 32, by = blockIdx.y * 32;
    int tx = threadIdx.x, ty = threadIdx.y;
#pragma unroll
    for (int j = 0; j < 32; j += 8)
        t[ty + j][tx] = W[(size_t)(by + ty + j) * 1024 + bx + tx];
    __syncthreads();
#pragma unroll
    for (int j = 0; j < 32; j += 8)
        Wt[(size_t)(bx + ty + j) * 1024 + by + tx] = (bf16)t[tx][ty + j];
}

// ---------------------------------------------------------------- GEMM C=A@Bt^T
// A: MMxKK bf16 row-major, Bt: NNxKK bf16 row-major (i.e. B transposed)
// tile 64x128, BK=64, 256 threads = 4 waves, wave w covers cols w*32 (2 nfrag)
// MODE 0: Cb bf16 row-major   MODE 1: Vt[b][h][dv][tok]   MODE 2: Cf=acc+resid
template <int MODE>
__global__ __launch_bounds__(256) void k_gemm(const bf16* __restrict__ A,
                                              const bf16* __restrict__ Bt,
                                              bf16* __restrict__ Cb,
                                              float* __restrict__ Cf,
                                              const float* __restrict__ resid) {
    __shared__ __align__(16) char AsB[64 * LDS_STRIDE];
    __shared__ __align__(16) char BsB[128 * LDS_STRIDE];
    const int tid = threadIdx.x, lane = tid & 63, w = tid >> 6;
    const int g = lane >> 4, li = lane & 15;
    const int bm0 = blockIdx.x * 64, bn0 = blockIdx.y * 128;

    f32x4 zz = {0.f, 0.f, 0.f, 0.f};
    f32x4 acc[4][2];
#pragma unroll
    for (int mf = 0; mf < 4; ++mf)
#pragma unroll
        for (int nf = 0; nf < 2; ++nf) acc[mf][nf] = zz;

    for (int k0 = 0; k0 < KK; k0 += 64) {
        __syncthreads();
        // stage A: 64 rows x 8 chunks(16B) = 512 chunks
#pragma unroll
        for (int i = 0; i < 2; ++i) {
            int e = i * 256 + tid;
            int row = e >> 3, c = e & 7;
            bf16x8 t = *(const bf16x8*)((const char*)A +
                         ((size_t)(bm0 + row) * KK + k0) * 2 + c * 16);
            *(bf16x8*)(AsB + row * LDS_STRIDE + c * 16) = t;
        }
        // stage B: 128 rows x 8 chunks = 1024 chunks
#pragma unroll
        for (int i = 0; i < 4; ++i) {
            int e = i * 256 + tid;
            int row = e >> 3, c = e & 7;
            bf16x8 t = *(const bf16x8*)((const char*)Bt +
                         ((size_t)(bn0 + row) * KK + k0) * 2 + c * 16);
            *(bf16x8*)(BsB + row * LDS_STRIDE + c * 16) = t;
        }
        __syncthreads();
#pragma unroll
        for (int kk = 0; kk < 2; ++kk) {
            const int kb = kk * 64 + (g << 4);
            bf16x8 bfr[2];
#pragma unroll
            for (int nf = 0; nf < 2; ++nf) {
                int rn = w * 32 + nf * 16 + li;
                bfr[nf] = *(const bf16x8*)(BsB + rn * LDS_STRIDE + kb);
            }
#pragma unroll
            for (int mf = 0; mf < 4; ++mf) {
                int rm = mf * 16 + li;
                bf16x8 afr = *(const bf16x8*)(AsB + rm * LDS_STRIDE + kb);
                acc[mf][0] = __builtin_amdgcn_mfma_f32_16x16x32_bf16(
                    afr, bfr[0], acc[mf][0], 0, 0, 0);
                acc[mf][1] = __builtin_amdgcn_mfma_f32_16x16x32_bf16(
                    afr, bfr[1], acc[mf][1], 0, 0, 0);
            }
        }
    }
    // epilogue: C layout col = lane&15, row = (lane>>4)*4 + r
#pragma unroll
    for (int mf = 0; mf < 4; ++mf)
#pragma unroll
        for (int nf = 0; nf < 2; ++nf) {
            int n = bn0 + w * 32 + nf * 16 + li;
            int m0 = bm0 + mf * 16 + (g << 2);
            if (MODE == 0) {
#pragma unroll
                for (int r = 0; r < 4; ++r)
                    Cb[(size_t)(m0 + r) * NN + n] = (bf16)acc[mf][nf][r];
            } else if (MODE == 1) {
                int bq = m0 >> 11, tok = m0 & (N_ - 1);
                int hh = n >> 6, dv = n & 63;
                bf4 val;
#pragma unroll
                for (int r = 0; r < 4; ++r) val.v[r] = (bf16)acc[mf][nf][r];
                *(bf4*)(Cb + ((size_t)((bq * H_ + hh) * 64 + dv)) * N_ + tok) = val;
            } else {
#pragma unroll
                for (int r = 0; r < 4; ++r) {
                    size_t ix = (size_t)(m0 + r) * NN + n;
                    Cf[ix] = acc[mf][nf][r] + resid[ix];
                }
            }
        }
}

// ---------------------------------------------------------------- attention
// per block: (b, h, 64 q-rows). Two-pass online softmax; writes attn (f32) and
// O (bf16, (B,N,H*DV) layout). Qh/Kh: (B,N,H*DK) bf16. Vt: (B,H,DV,N) bf16.
__global__ __launch_bounds__(256) void k_attn(const bf16* __restrict__ Qh,
                                              const bf16* __restrict__ Kh,
                                              const bf16* __restrict__ Vt,
                                              const int* __restrict__ mask,
                                              float* __restrict__ attnp,
                                              bf16* __restrict__ Ob) {
    __shared__ __align__(16) char Qs[64 * LDS_STRIDE];
    __shared__ __align__(16) char Ks[64 * LDS_STRIDE];
    __shared__ __align__(16) char Vs[64 * LDS_STRIDE];
    __shared__ __align__(16) char Ps[64 * LDS_STRIDE];
    const int tid = threadIdx.x, lane = tid & 63, w = tid >> 6;
    const int g = lane >> 4, li = lane & 15;
    const int i0 = blockIdx.x * 64;
    const int h = blockIdx.y, b = blockIdx.z;
    const size_t mbase = (size_t)b * N_ * N_;
    const size_t abase = (((size_t)b * H_ + h) * N_ + i0) * N_;

    // stage Q once
#pragma unroll
    for (int i = 0; i < 2; ++i) {
        int e = i * 256 + tid;
        int row = e >> 3, c = e & 7;
        bf16x8 t = *(const bf16x8*)((const char*)Qh +
                     ((size_t)(b * N_ + i0 + row) * D_ + h * 64) * 2 + c * 16);
        *(bf16x8*)(Qs + row * LDS_STRIDE + c * 16) = t;
    }

    const int jt_max = i0 >> 6;
    float m[4], l[4];
#pragma unroll
    for (int r = 0; r < 4; ++r) { m[r] = -__builtin_inff(); l[r] = 0.f; }

    f32x4 zz = {0.f, 0.f, 0.f, 0.f};

    // ---- pass A: stats
    for (int jt = 0; jt <= jt_max; ++jt) {
        __syncthreads();
        int j0 = jt * 64;
#pragma unroll
        for (int i = 0; i < 2; ++i) {
            int e = i * 256 + tid;
            int row = e >> 3, c = e & 7;
            bf16x8 t = *(const bf16x8*)((const char*)Kh +
                         ((size_t)(b * N_ + j0 + row) * D_ + h * 64) * 2 + c * 16);
            *(bf16x8*)(Ks + row * LDS_STRIDE + c * 16) = t;
        }
        __syncthreads();
        f32x4 s[4];
#pragma unroll
        for (int nf = 0; nf < 4; ++nf) s[nf] = zz;
#pragma unroll
        for (int kk = 0; kk < 2; ++kk) {
            int kb = kk * 64 + (g << 4);
            int rq = w * 16 + li;
            bf16x8 a = *(const bf16x8*)(Qs + rq * LDS_STRIDE + kb);
#pragma unroll
            for (int nf = 0; nf < 4; ++nf) {
                int rk = nf * 16 + li;
                bf16x8 bb = *(const bf16x8*)(Ks + rk * LDS_STRIDE + kb);
                s[nf] = __builtin_amdgcn_mfma_f32_16x16x32_bf16(a, bb, s[nf], 0, 0, 0);
            }
        }
#pragma unroll
        for (int r = 0; r < 4; ++r) {
            int gi = i0 + w * 16 + g * 4 + r;
            float sv[4];
            float tmax = -__builtin_inff();
#pragma unroll
            for (int nf = 0; nf < 4; ++nf) {
                int gj = j0 + nf * 16 + li;
                float x = s[nf][r] * 0.125f;
                bool ok = (gj <= gi) && (mask[mbase + (size_t)gi * N_ + gj] != 0);
                x = ok ? x : -1e9f;
                sv[nf] = x;
                tmax = fmaxf(tmax, x);
            }
#pragma unroll
            for (int o = 1; o < 16; o <<= 1) tmax = fmaxf(tmax, __shfl_xor(tmax, o));
            float mn = fmaxf(m[r], tmax);
            float ps = 0.f;
#pragma unroll
            for (int nf = 0; nf < 4; ++nf) ps += __expf(sv[nf] - mn);
#pragma unroll
            for (int o = 1; o < 16; o <<= 1) ps += __shfl_xor(ps, o);
            l[r] = l[r] * __expf(m[r] - mn) + ps;
            m[r] = mn;
        }
    }

    float linv[4];
#pragma unroll
    for (int r = 0; r < 4; ++r) linv[r] = 1.f / l[r];

    f32x4 oacc[4];
#pragma unroll
    for (int nf = 0; nf < 4; ++nf) oacc[nf] = zz;

    // ---- pass B: write P, accumulate O = P @ V
    for (int jt = 0; jt <= jt_max; ++jt) {
        __syncthreads();
        int j0 = jt * 64;
#pragma unroll
        for (int i = 0; i < 2; ++i) {
            int e = i * 256 + tid;
            int row = e >> 3, c = e & 7;
            bf16x8 t = *(const bf16x8*)((const char*)Kh +
                         ((size_t)(b * N_ + j0 + row) * D_ + h * 64) * 2 + c * 16);
            *(bf16x8*)(Ks + row * LDS_STRIDE + c * 16) = t;
            bf16x8 tv = *(const bf16x8*)((const char*)Vt +
                         (((size_t)(b * H_ + h) * 64 + row) * N_ + j0) * 2 + c * 16);
            *(bf16x8*)(Vs + row * LDS_STRIDE + c * 16) = tv;
        }
        __syncthreads();
        f32x4 s[4];
#pragma unroll
        for (int nf = 0; nf < 4; ++nf) s[nf] = zz;
#pragma unroll
        for (int kk = 0; kk < 2; ++kk) {
            int kb = kk * 64 + (g << 4);
            int rq = w * 16 + li;
            bf16x8 a = *(const bf16x8*)(Qs + rq * LDS_STRIDE + kb);
#pragma unroll
            for (int nf = 0; nf < 4; ++nf) {
                int rk = nf * 16 + li;
                bf16x8 bb = *(const bf16x8*)(Ks + rk * LDS_STRIDE + kb);
                s[nf] = __builtin_amdgcn_mfma_f32_16x16x32_bf16(a, bb, s[nf], 0, 0, 0);
            }
        }
#pragma unroll
        for (int r = 0; r < 4; ++r) {
            int gi = i0 + w * 16 + g * 4 + r;
            int rowl = w * 16 + g * 4 + r;
#pragma unroll
            for (int nf = 0; nf < 4; ++nf) {
                int gj = j0 + nf * 16 + li;
                float x = s[nf][r] * 0.125f;
                bool ok = (gj <= gi) && (mask[mbase + (size_t)gi * N_ + gj] != 0);
                x = ok ? x : -1e9f;
                float p = __expf(x - m[r]) * linv[r];
                attnp[abase + (size_t)(w * 16 + g * 4 + r) * N_ + gj] = p;
                *(bf16*)(Ps + rowl * LDS_STRIDE + (nf * 16 + li) * 2) = (bf16)p;
            }
        }
        // PV: Ps rows of this wave written by this wave only -> no barrier
#pragma unroll
        for (int kk = 0; kk < 2; ++kk) {
            int kb = kk * 64 + (g << 4);
            int rp = w * 16 + li;
            bf16x8 a = *(const bf16x8*)(Ps + rp * LDS_STRIDE + kb);
#pragma unroll
            for (int nf = 0; nf < 4; ++nf) {
                int rv = nf * 16 + li;
                bf16x8 bb = *(const bf16x8*)(Vs + rv * LDS_STRIDE + kb);
                oacc[nf] = __builtin_amdgcn_mfma_f32_16x16x32_bf16(a, bb, oacc[nf], 0, 0, 0);
            }
        }
    }

    // write O: Ob[(b*N + gi)*D + h*64 + dv]
#pragma unroll
    for (int nf = 0; nf < 4; ++nf)
#pragma unroll
        for (int r = 0; r < 4; ++r) {
            int gi = i0 + w * 16 + g * 4 + r;
            int dv = nf * 16 + li;
            Ob[((size_t)(b * N_ + gi)) * D_ + h * 64 + dv] = (bf16)oacc[nf][r];
        }

    // zero-fill strictly-upper tiles: cols [i0+64, N)
    int zc0 = i0 + 64;
    if (zc0 < N_) {
        int r = tid >> 2, tc = tid & 3;
        f32x4 z = zz;
        for (int c = zc0 + tc * 4; c < N_; c += 16)
            *(f32x4*)(attnp + abase + (size_t)r * N_ + c) = z;
    }
}

// ---------------------------------------------------------------- layernorm
__global__ __launch_bounds__(256) void k_ln(float* __restrict__ out,
                                            const float* __restrict__ gamma,
                                            const float* __restrict__ beta) {
    const int row = blockIdx.x, t = threadIdx.x, lane = t & 63, w = t >> 6;
    float* p = out + (size_t)row * D_;
    f32x4 x = *(const f32x4*)(p + t * 4);
    float s = x[0] + x[1] + x[2] + x[3];
    float s2 = x[0] * x[0] + x[1] * x[1] + x[2] * x[2] + x[3] * x[3];
#pragma unroll
    for (int o = 1; o < 64; o <<= 1) {
        s += __shfl_xor(s, o);
        s2 += __shfl_xor(s2, o);
    }
    __shared__ float r1[4], r2[4];
    if (lane == 0) { r1[w] = s; r2[w] = s2; }
    __syncthreads();
    s = r1[0] + r1[1] + r1[2] + r1[3];
    s2 = r2[0] + r2[1] + r2[2] + r2[3];
    float mean = s * (1.f / D_);
    float var = s2 * (1.f / D_) - mean * mean;
    float rstd = rsqrtf(var + 1e-6f);
    f32x4 gv = *(const f32x4*)(gamma + t * 4);
    f32x4 bv = *(const f32x4*)(beta + t * 4);
    f32x4 y;
#pragma unroll
    for (int c = 0; c < 4; ++c) y[c] = (x[c] - mean) * rstd * gv[c] + bv[c];
    *(f32x4*)(p + t * 4) = y;
}

// ---------------------------------------------------------------- launch
extern "C" void kernel_launch(void* const* d_in, const int* in_sizes, int n_in,
                              void* d_out, int out_size, void* d_ws,
                              size_t ws_size, hipStream_t stream) {
    (void)in_sizes; (void)n_in; (void)out_size; (void)ws_size;
    const float* q = (const float*)d_in[0];
    const float* k = (const float*)d_in[1];
    const float* v = (const float*)d_in[2];
    const int* msk = (const int*)d_in[3];
    const float* Wq = (const float*)d_in[4];
    const float* Wk = (const float*)d_in[5];
    const float* Wv = (const float*)d_in[6];
    const float* Wo = (const float*)d_in[7];
    const float* gamma = (const float*)d_in[8];
    const float* beta = (const float*)d_in[9];

    float* outp = (float*)d_out;
    float* attnp = outp + (size_t)B_ * N_ * D_;

    const size_t U = (size_t)B_ * N_ * D_;   // 4,194,304
    const size_t W1 = (size_t)D_ * D_;       // 1,048,576
    bf16* ws = (bf16*)d_ws;
    bf16* qb = ws;   ws += U;
    bf16* kb = ws;   ws += U;
    bf16* vb = ws;   ws += U;
    bf16* WqT = ws;  ws += W1;
    bf16* WkT = ws;  ws += W1;
    bf16* WvT = ws;  ws += W1;
    bf16* WoT = ws;  ws += W1;
    bf16* Qh = ws;   ws += U;
    bf16* Kh = ws;   ws += U;
    bf16* Vt = ws;   ws += U;   // (B,H,DV,N) = same element count
    bf16* Ob = ws;   ws += U;

    k_cvt<<<U / 4 / 256, 256, 0, stream>>>(q, qb);
    k_cvt<<<U / 4 / 256, 256, 0, stream>>>(k, kb);
    k_cvt<<<U / 4 / 256, 256, 0, stream>>>(v, vb);
    dim3 tb(32, 8);
    k_wtt<<<dim3(32, 32), tb, 0, stream>>>(Wq, WqT);
    k_wtt<<<dim3(32, 32), tb, 0, stream>>>(Wk, WkT);
    k_wtt<<<dim3(32, 32), tb, 0, stream>>>(Wv, WvT);
    k_wtt<<<dim3(32, 32), tb, 0, stream>>>(Wo, WoT);

    dim3 gg(MM / 64, NN / 128);
    k_gemm<0><<<gg, 256, 0, stream>>>(qb, WqT, Qh, nullptr, nullptr);
    k_gemm<0><<<gg, 256, 0, stream>>>(kb, WkT, Kh, nullptr, nullptr);
    k_gemm<1><<<gg, 256, 0, stream>>>(vb, WvT, Vt, nullptr, nullptr);

    k_attn<<<dim3(N_ / 64, H_, B_), 256, 0, stream>>>(Qh, Kh, Vt, msk, attnp, Ob);

    k_gemm<2><<<gg, 256, 0, stream>>>(Ob, WoT, nullptr, outp, q);

    k_ln<<<B_ * N_, 256, 0, stream>>>(outp, gamma, beta);
}

// Round 2
// 285.894 us; speedup vs baseline: 3.3343x; 3.3343x over previous
//
#include <hip/hip_runtime.h>
#include <hip/hip_bf16.h>
#include <stdint.h>

#define B_ 2
#define N_ 2048
#define D_ 1024
#define H_ 16
#define MM 4096
#define NN 1024
#define KK 1024

typedef __bf16 bf16;
typedef __bf16 bf16x8 __attribute__((ext_vector_type(8)));
typedef float f32x4 __attribute__((ext_vector_type(4)));

struct __align__(8) bf4 { bf16 v[4]; };

// 64 bf16 + 8 pad = 144 B row stride (multiple of 16 -> b128-aligned)
#define LDS_STRIDE 144

// ---------------------------------------------------------------- weights^T
__global__ void k_wtt(const float* __restrict__ W, bf16* __restrict__ Wt) {
    __shared__ float t[32][33];
    int bx = blockIdx.x * 32, by = blockIdx.y * 32;
    int tx = threadIdx.x, ty = threadIdx.y;
#pragma unroll
    for (int j = 0; j < 32; j += 8)
        t[ty + j][tx] = W[(size_t)(by + ty + j) * 1024 + bx + tx];
    __syncthreads();
#pragma unroll
    for (int j = 0; j < 32; j += 8)
        Wt[(size_t)(bx + ty + j) * 1024 + by + tx] = (bf16)t[tx][ty + j];
}

// ---------------------------------------------------------------- mask bits
// bits[b][i][w] (uint32, 64 words/row): bit j = mask && (col<=row)  (causal folded)
__global__ __launch_bounds__(256) void k_bits(const int* __restrict__ mask,
                                              uint32_t* __restrict__ bits) {
    size_t flat = (size_t)blockIdx.x * 256 + threadIdx.x;
    int col = (int)(flat & (N_ - 1));
    int row = (int)((flat >> 11) & (N_ - 1));
    bool ok = (mask[flat] != 0) && (col <= row);
    unsigned long long bal = __ballot(ok);
    if ((threadIdx.x & 63) == 0)
        *(unsigned long long*)(bits + (flat >> 5)) = bal;
}

// ---------------------------------------------------------------- GEMM C=A@Bt^T
// A: MMxKK (bf16 or f32) row-major, Bt: NNxKK bf16 (B transposed)
// tile 64x128, BK=64, 4 waves. MODE 0: Cb bf16 (scaled); MODE 1: Vt[b][h][dv][tok];
// MODE 2: Cf = acc + resid
template <int MODE, bool AF32>
__global__ __launch_bounds__(256) void k_gemm(const void* __restrict__ Av,
                                              const bf16* __restrict__ Bt,
                                              bf16* __restrict__ Cb,
                                              float* __restrict__ Cf,
                                              const float* __restrict__ resid,
                                              float scale) {
    __shared__ __align__(16) char AsB[64 * LDS_STRIDE];
    __shared__ __align__(16) char BsB[128 * LDS_STRIDE];
    const int tid = threadIdx.x, lane = tid & 63, w = tid >> 6;
    const int g = lane >> 4, li = lane & 15;
    const int bm0 = blockIdx.x * 64, bn0 = blockIdx.y * 128;
    const int srow = tid >> 3, sc = tid & 7;
    const bf16* Ab = (const bf16*)Av;
    const float* Af = (const float*)Av;

    f32x4 zz = {0.f, 0.f, 0.f, 0.f};
    f32x4 acc[4][2];
#pragma unroll
    for (int mf = 0; mf < 4; ++mf)
#pragma unroll
        for (int nf = 0; nf < 2; ++nf) acc[mf][nf] = zz;

    f32x4 pa0[2], pa1[2];
    bf16x8 pab[2];
    bf16x8 pb[4];

    auto issueA = [&](int k0) {
        if constexpr (AF32) {
#pragma unroll
            for (int i = 0; i < 2; ++i) {
                const float* s = Af + (size_t)(bm0 + srow + 32 * i) * KK + k0 + sc * 8;
                pa0[i] = *(const f32x4*)s;
                pa1[i] = *(const f32x4*)(s + 4);
            }
        } else {
#pragma unroll
            for (int i = 0; i < 2; ++i)
                pab[i] = *(const bf16x8*)(Ab + (size_t)(bm0 + srow + 32 * i) * KK + k0 + sc * 8);
        }
    };
    auto issueB = [&](int k0) {
#pragma unroll
        for (int i = 0; i < 4; ++i)
            pb[i] = *(const bf16x8*)(Bt + (size_t)(bn0 + srow + 32 * i) * KK + k0 + sc * 8);
    };
    auto writeS = [&]() {
#pragma unroll
        for (int i = 0; i < 2; ++i) {
            bf16x8 t;
            if constexpr (AF32) {
#pragma unroll
                for (int j = 0; j < 4; ++j) {
                    t[j] = (bf16)pa0[i][j];
                    t[4 + j] = (bf16)pa1[i][j];
                }
            } else {
                t = pab[i];
            }
            *(bf16x8*)(AsB + (srow + 32 * i) * LDS_STRIDE + sc * 16) = t;
        }
#pragma unroll
        for (int i = 0; i < 4; ++i)
            *(bf16x8*)(BsB + (srow + 32 * i) * LDS_STRIDE + sc * 16) = pb[i];
    };

    issueA(0);
    issueB(0);
    for (int k0 = 0; k0 < KK; k0 += 64) {
        __syncthreads();
        writeS();
        int kn = (k0 + 64 < KK) ? k0 + 64 : k0;
        issueA(kn);
        issueB(kn);
        __syncthreads();
#pragma unroll
        for (int kk = 0; kk < 2; ++kk) {
            const int kb = kk * 64 + (g << 4);
            bf16x8 bfr[2];
#pragma unroll
            for (int nf = 0; nf < 2; ++nf) {
                int rn = w * 32 + nf * 16 + li;
                bfr[nf] = *(const bf16x8*)(BsB + rn * LDS_STRIDE + kb);
            }
#pragma unroll
            for (int mf = 0; mf < 4; ++mf) {
                int rm = mf * 16 + li;
                bf16x8 afr = *(const bf16x8*)(AsB + rm * LDS_STRIDE + kb);
                acc[mf][0] = __builtin_amdgcn_mfma_f32_16x16x32_bf16(
                    afr, bfr[0], acc[mf][0], 0, 0, 0);
                acc[mf][1] = __builtin_amdgcn_mfma_f32_16x16x32_bf16(
                    afr, bfr[1], acc[mf][1], 0, 0, 0);
            }
        }
    }
#pragma unroll
    for (int mf = 0; mf < 4; ++mf)
#pragma unroll
        for (int nf = 0; nf < 2; ++nf) {
            int n = bn0 + w * 32 + nf * 16 + li;
            int m0 = bm0 + mf * 16 + (g << 2);
            if (MODE == 0) {
#pragma unroll
                for (int r = 0; r < 4; ++r)
                    Cb[(size_t)(m0 + r) * NN + n] = (bf16)(acc[mf][nf][r] * scale);
            } else if (MODE == 1) {
                int bq = m0 >> 11, tok = m0 & (N_ - 1);
                int hh = n >> 6, dv = n & 63;
                bf4 val;
#pragma unroll
                for (int r = 0; r < 4; ++r) val.v[r] = (bf16)(acc[mf][nf][r] * scale);
                *(bf4*)(Cb + ((size_t)((bq * H_ + hh) * 64 + dv)) * N_ + tok) = val;
            } else {
#pragma unroll
                for (int r = 0; r < 4; ++r) {
                    size_t ix = (size_t)(m0 + r) * NN + n;
                    Cf[ix] = acc[mf][nf][r] + resid[ix];
                }
            }
        }
}

// ---------------------------------------------------------------- attention
// Block = (pair p, h, b): handles qt = p and qt = 31-p (balanced: 66 tile-iters).
// Swapped QK^T: S^T = mfma(K, Q) -> lane (li,g) owns q-row w*16+li, k-cols
// {mf*16+g*4+r}. Row softmax = local 16-max + shfl_xor(16,32). P written to attn
// as f32x4, packed bf16 to Ps for PV.
__global__ __launch_bounds__(256) void k_attn(const bf16* __restrict__ Qh,
                                              const bf16* __restrict__ Kh,
                                              const bf16* __restrict__ Vt,
                                              const uint32_t* __restrict__ bits,
                                              float* __restrict__ attnp,
                                              bf16* __restrict__ Ob) {
    __shared__ __align__(16) char Qs[64 * LDS_STRIDE];
    __shared__ __align__(16) char Ks[64 * LDS_STRIDE];
    __shared__ __align__(16) char Vs[64 * LDS_STRIDE];
    __shared__ __align__(16) char Ps[64 * LDS_STRIDE];
    const int tid = threadIdx.x, lane = tid & 63, w = tid >> 6;
    const int g = lane >> 4, li = lane & 15;
    const int p = blockIdx.x, h = blockIdx.y, b = blockIdx.z;
    const int srow = tid >> 3, sc = tid & 7;
    const int myrow = w * 16 + li;  // this lane's q-row within tile

    const size_t kbase = ((size_t)b * N_) * D_ + h * 64;           // Q/K col base
    const size_t vbase = ((size_t)(b * H_ + h) * 64) * N_;         // Vt base
    f32x4 zz = {0.f, 0.f, 0.f, 0.f};

    for (int half = 0; half < 2; ++half) {
        const int qt = half ? (31 - p) : p;
        const int i0 = qt << 6;
        const size_t abase = (((size_t)b * H_ + h) * N_ + i0) * (size_t)N_;

        __syncthreads();  // previous half's LDS reads done
        // stage Q tile (rows i0..i0+63)
        {
            const char* qsrc = (const char*)Qh +
                (kbase + (size_t)(i0 + srow) * D_ + sc * 8) * 2;
            bf16x8 t0 = *(const bf16x8*)qsrc;
            bf16x8 t1 = *(const bf16x8*)(qsrc + (size_t)32 * D_ * 2);
            *(bf16x8*)(Qs + srow * LDS_STRIDE + sc * 16) = t0;
            *(bf16x8*)(Qs + (srow + 32) * LDS_STRIDE + sc * 16) = t1;
        }
        const uint32_t* mrow = bits + (((size_t)b * N_ + i0 + myrow) << 6);

        // ================= pass A: row stats =================
        float m = -1e30f, l = 0.f;
        bf16x8 ka, kb2;
        {
            const char* ks = (const char*)Kh + (kbase + (size_t)srow * D_ + sc * 8) * 2;
            ka = *(const bf16x8*)ks;
            kb2 = *(const bf16x8*)(ks + (size_t)32 * D_ * 2);
        }
        for (int jt = 0; jt <= qt; ++jt) {
            __syncthreads();
            *(bf16x8*)(Ks + srow * LDS_STRIDE + sc * 16) = ka;
            *(bf16x8*)(Ks + (srow + 32) * LDS_STRIDE + sc * 16) = kb2;
            {
                int jn = (jt < qt) ? jt + 1 : qt;
                const char* ks = (const char*)Kh +
                    (kbase + (size_t)(jn * 64 + srow) * D_ + sc * 8) * 2;
                ka = *(const bf16x8*)ks;
                kb2 = *(const bf16x8*)(ks + (size_t)32 * D_ * 2);
            }
            uint2 mw = *(const uint2*)(mrow + (jt << 1));
            __syncthreads();

            f32x4 s[4];
#pragma unroll
            for (int mf = 0; mf < 4; ++mf) s[mf] = zz;
#pragma unroll
            for (int kk = 0; kk < 2; ++kk) {
                const int kb = kk * 64 + (g << 4);
                bf16x8 qf = *(const bf16x8*)(Qs + myrow * LDS_STRIDE + kb);
#pragma unroll
                for (int mf = 0; mf < 4; ++mf) {
                    bf16x8 kf = *(const bf16x8*)(Ks + (mf * 16 + li) * LDS_STRIDE + kb);
                    s[mf] = __builtin_amdgcn_mfma_f32_16x16x32_bf16(kf, qf, s[mf], 0, 0, 0);
                }
            }
            float tmax = m;
#pragma unroll
            for (int mf = 0; mf < 4; ++mf) {
                uint32_t wsel = (mf < 2) ? mw.x : mw.y;
#pragma unroll
                for (int r = 0; r < 4; ++r) {
                    int sh = (mf & 1) * 16 + g * 4 + r;
                    float xv = ((wsel >> sh) & 1) ? s[mf][r] : -1e9f;
                    s[mf][r] = xv;
                    tmax = fmaxf(tmax, xv);
                }
            }
            tmax = fmaxf(tmax, __shfl_xor(tmax, 16));
            tmax = fmaxf(tmax, __shfl_xor(tmax, 32));
            float ps = 0.f;
#pragma unroll
            for (int mf = 0; mf < 4; ++mf)
#pragma unroll
                for (int r = 0; r < 4; ++r) ps += __expf(s[mf][r] - tmax);
            ps += __shfl_xor(ps, 16);
            ps += __shfl_xor(ps, 32);
            l = l * __expf(m - tmax) + ps;
            m = tmax;
        }
        const float linv = 1.0f / l;

        // ================= pass B: P + O =================
        f32x4 oacc[4];
#pragma unroll
        for (int nf = 0; nf < 4; ++nf) oacc[nf] = zz;

        bf16x8 va, vb2;
        {
            const char* ks = (const char*)Kh + (kbase + (size_t)srow * D_ + sc * 8) * 2;
            ka = *(const bf16x8*)ks;
            kb2 = *(const bf16x8*)(ks + (size_t)32 * D_ * 2);
            const char* vs = (const char*)Vt + (vbase + (size_t)srow * N_ + sc * 8) * 2;
            va = *(const bf16x8*)vs;
            vb2 = *(const bf16x8*)(vs + (size_t)32 * N_ * 2);
        }
        for (int jt = 0; jt <= qt; ++jt) {
            __syncthreads();
            *(bf16x8*)(Ks + srow * LDS_STRIDE + sc * 16) = ka;
            *(bf16x8*)(Ks + (srow + 32) * LDS_STRIDE + sc * 16) = kb2;
            *(bf16x8*)(Vs + srow * LDS_STRIDE + sc * 16) = va;
            *(bf16x8*)(Vs + (srow + 32) * LDS_STRIDE + sc * 16) = vb2;
            {
                int jn = (jt < qt) ? jt + 1 : qt;
                const char* ks = (const char*)Kh +
                    (kbase + (size_t)(jn * 64 + srow) * D_ + sc * 8) * 2;
                ka = *(const bf16x8*)ks;
                kb2 = *(const bf16x8*)(ks + (size_t)32 * D_ * 2);
                const char* vs = (const char*)Vt +
                    (vbase + (size_t)srow * N_ + jn * 64 + sc * 8) * 2;
                va = *(const bf16x8*)vs;
                vb2 = *(const bf16x8*)(vs + (size_t)32 * N_ * 2);
            }
            uint2 mw = *(const uint2*)(mrow + (jt << 1));
            __syncthreads();

            f32x4 s[4];
#pragma unroll
            for (int mf = 0; mf < 4; ++mf) s[mf] = zz;
#pragma unroll
            for (int kk = 0; kk < 2; ++kk) {
                const int kb = kk * 64 + (g << 4);
                bf16x8 qf = *(const bf16x8*)(Qs + myrow * LDS_STRIDE + kb);
#pragma unroll
                for (int mf = 0; mf < 4; ++mf) {
                    bf16x8 kf = *(const bf16x8*)(Ks + (mf * 16 + li) * LDS_STRIDE + kb);
                    s[mf] = __builtin_amdgcn_mfma_f32_16x16x32_bf16(kf, qf, s[mf], 0, 0, 0);
                }
            }
#pragma unroll
            for (int mf = 0; mf < 4; ++mf) {
                uint32_t wsel = (mf < 2) ? mw.x : mw.y;
#pragma unroll
                for (int r = 0; r < 4; ++r) {
                    int sh = (mf & 1) * 16 + g * 4 + r;
                    float xv = ((wsel >> sh) & 1) ? s[mf][r] : -1e9f;
                    s[mf][r] = __expf(xv - m) * linv;
                }
                // attn store: 16B contiguous, rows of 64B per wave-quarter
                *(f32x4*)(attnp + abase + (size_t)myrow * N_ + (jt << 6) + mf * 16 + g * 4) = s[mf];
                bf4 pk;
#pragma unroll
                for (int r = 0; r < 4; ++r) pk.v[r] = (bf16)s[mf][r];
                *(bf4*)(Ps + myrow * LDS_STRIDE + (mf * 16 + g * 4) * 2) = pk;
            }
            // PV (Ps rows written/read by same wave; in-wave LDS order suffices)
#pragma unroll
            for (int kk = 0; kk < 2; ++kk) {
                const int kb = kk * 64 + (g << 4);
                bf16x8 pf = *(const bf16x8*)(Ps + myrow * LDS_STRIDE + kb);
#pragma unroll
                for (int nf = 0; nf < 4; ++nf) {
                    bf16x8 vf = *(const bf16x8*)(Vs + (nf * 16 + li) * LDS_STRIDE + kb);
                    oacc[nf] = __builtin_amdgcn_mfma_f32_16x16x32_bf16(pf, vf, oacc[nf], 0, 0, 0);
                }
            }
        }
        // O store: row = i0 + w*16 + g*4 + r, col dv = nf*16 + li
#pragma unroll
        for (int nf = 0; nf < 4; ++nf)
#pragma unroll
            for (int r = 0; r < 4; ++r) {
                int gi = i0 + w * 16 + g * 4 + r;
                Ob[((size_t)(b * N_ + gi)) * D_ + h * 64 + nf * 16 + li] = (bf16)oacc[nf][r];
            }
        // zero-fill strictly-upper tiles: cols [i0+64, N)
        int zc0 = i0 + 64;
        if (zc0 < N_) {
            int r = tid >> 2, tc = tid & 3;
            f32x4 z = zz;
            for (int c = zc0 + tc * 4; c < N_; c += 16)
                *(f32x4*)(attnp + abase + (size_t)r * N_ + c) = z;
        }
    }
}

// ---------------------------------------------------------------- layernorm
__global__ __launch_bounds__(256) void k_ln(float* __restrict__ out,
                                            const float* __restrict__ gamma,
                                            const float* __restrict__ beta) {
    const int row = blockIdx.x, t = threadIdx.x, lane = t & 63, w = t >> 6;
    float* p = out + (size_t)row * D_;
    f32x4 x = *(const f32x4*)(p + t * 4);
    float s = x[0] + x[1] + x[2] + x[3];
    float s2 = x[0] * x[0] + x[1] * x[1] + x[2] * x[2] + x[3] * x[3];
#pragma unroll
    for (int o = 1; o < 64; o <<= 1) {
        s += __shfl_xor(s, o);
        s2 += __shfl_xor(s2, o);
    }
    __shared__ float r1[4], r2[4];
    if (lane == 0) { r1[w] = s; r2[w] = s2; }
    __syncthreads();
    s = r1[0] + r1[1] + r1[2] + r1[3];
    s2 = r2[0] + r2[1] + r2[2] + r2[3];
    float mean = s * (1.f / D_);
    float var = s2 * (1.f / D_) - mean * mean;
    float rstd = rsqrtf(var + 1e-6f);
    f32x4 gv = *(const f32x4*)(gamma + t * 4);
    f32x4 bv = *(const f32x4*)(beta + t * 4);
    f32x4 y;
#pragma unroll
    for (int c = 0; c < 4; ++c) y[c] = (x[c] - mean) * rstd * gv[c] + bv[c];
    *(f32x4*)(p + t * 4) = y;
}

// ---------------------------------------------------------------- launch
extern "C" void kernel_launch(void* const* d_in, const int* in_sizes, int n_in,
                              void* d_out, int out_size, void* d_ws,
                              size_t ws_size, hipStream_t stream) {
    (void)in_sizes; (void)n_in; (void)out_size; (void)ws_size;
    const float* q = (const float*)d_in[0];
    const float* k = (const float*)d_in[1];
    const float* v = (const float*)d_in[2];
    const int* msk = (const int*)d_in[3];
    const float* Wq = (const float*)d_in[4];
    const float* Wk = (const float*)d_in[5];
    const float* Wv = (const float*)d_in[6];
    const float* Wo = (const float*)d_in[7];
    const float* gamma = (const float*)d_in[8];
    const float* beta = (const float*)d_in[9];

    float* outp = (float*)d_out;
    float* attnp = outp + (size_t)B_ * N_ * D_;

    const size_t U = (size_t)B_ * N_ * D_;   // 4,194,304
    const size_t W1 = (size_t)D_ * D_;       // 1,048,576
    bf16* ws = (bf16*)d_ws;
    bf16* WqT = ws;  ws += W1;
    bf16* WkT = ws;  ws += W1;
    bf16* WvT = ws;  ws += W1;
    bf16* WoT = ws;  ws += W1;
    bf16* Qh = ws;   ws += U;
    bf16* Kh = ws;   ws += U;
    bf16* Vt = ws;   ws += U;   // (B,H,DV,N)
    bf16* Ob = ws;   ws += U;
    uint32_t* bits = (uint32_t*)ws;  // B*N*N/32 words = 1 MB

    dim3 tb(32, 8);
    k_wtt<<<dim3(32, 32), tb, 0, stream>>>(Wq, WqT);
    k_wtt<<<dim3(32, 32), tb, 0, stream>>>(Wk, WkT);
    k_wtt<<<dim3(32, 32), tb, 0, stream>>>(Wv, WvT);
    k_wtt<<<dim3(32, 32), tb, 0, stream>>>(Wo, WoT);
    k_bits<<<(size_t)B_ * N_ * N_ / 256, 256, 0, stream>>>(msk, bits);

    dim3 gg(MM / 64, NN / 128);
    k_gemm<0, true><<<gg, 256, 0, stream>>>(q, WqT, Qh, nullptr, nullptr, 0.125f);
    k_gemm<0, true><<<gg, 256, 0, stream>>>(k, WkT, Kh, nullptr, nullptr, 1.0f);
    k_gemm<1, true><<<gg, 256, 0, stream>>>(v, WvT, Vt, nullptr, nullptr, 1.0f);

    k_attn<<<dim3(16, H_, B_), 256, 0, stream>>>(Qh, Kh, Vt, bits, attnp, Ob);

    k_gemm<2, false><<<gg, 256, 0, stream>>>(Ob, WoT, nullptr, outp, q, 1.0f);

    k_ln<<<B_ * N_, 256, 0, stream>>>(outp, gamma, beta);
}